// Round 2
// baseline (6549.243 us; speedup 1.0000x reference)
//
#include <hip/hip_runtime.h>

// MyRnn: 2-layer SimpleRNN, B=1024 T=80 U=1024 E=100. f32 I/O, f16 MFMA compute.
// v5: PERSISTENT kernel — the entire 80-step recurrence runs in ONE dispatch
// (512 blocks, 2/CU co-resident by construction: 64 KB LDS, __launch_bounds__(256,2)).
// Hand-rolled grid sync (monotonic agent-scope counter, release-add/acquire-spin)
// replaces 81 kernel launches; removes per-launch dispatch + L2 flush/inv teardown.
// Step GEMM interior unchanged from v4 (counted-vmcnt double-buffer pipeline).

typedef _Float16 h8v __attribute__((ext_vector_type(8)));
typedef float    f4v __attribute__((ext_vector_type(4)));
typedef short    s8v __attribute__((ext_vector_type(8)));

#define UNITS 1024
#define SEQ   80
#define EMBD  100
#define EPAD  128
#define KC    128
#define GRID  512

__device__ __forceinline__ float tanh_fast(float x) {
    x = fminf(15.f, fmaxf(-15.f, x));   // also scrubs NaN
    float e = __expf(2.f * x);
    return (e - 1.f) / (e + 1.f);
}

__device__ __forceinline__ void gl_lds16(const _Float16* g, _Float16* l) {
    __builtin_amdgcn_global_load_lds(
        (const __attribute__((address_space(1))) void*)g,
        (__attribute__((address_space(3))) void*)l, 16, 0, 0);
}

// embp[r][k] = k<100 ? (f16)emb[r][k] : 0   (10000 x 128)
__global__ void embp_kernel(const float* __restrict__ emb, _Float16* __restrict__ embp) {
    int r = blockIdx.x, k = threadIdx.x;
    embp[r * EPAD + k] = (k < EMBD) ? (_Float16)emb[r * EMBD + k] : (_Float16)0.f;
}

// wt[n][kp] = kp<K ? (f16)w[kp][n] : 0 ; wt row stride Kpad. block (32,8).
__global__ void tpad_kernel(const float* __restrict__ w, _Float16* __restrict__ wt,
                            int K, int Kpad, int N) {
    __shared__ float t[32][33];
    int k0 = blockIdx.x * 32, n0 = blockIdx.y * 32;
    int tx = threadIdx.x, ty = threadIdx.y;
    for (int i = ty; i < 32; i += 8) {
        int k = k0 + i;
        t[i][tx] = (k < K) ? w[(size_t)k * N + n0 + tx] : 0.f;
    }
    __syncthreads();
    for (int i = ty; i < 32; i += 8)
        wt[(size_t)(n0 + i) * Kpad + k0 + tx] = (_Float16)t[tx][i];
}

// blocks 0..2047 zero the 8 MB H region; block 2048 zeros the sync counter
__global__ void zero_kernel(s8v* __restrict__ p, unsigned* __restrict__ cnt) {
    if (blockIdx.x == 2048) {
        if (threadIdx.x == 0) *cnt = 0u;
        return;
    }
    p[blockIdx.x * 256 + threadIdx.x] = (s8v)0;
}

struct PArgs {
    const int* x;            // [1024][80]
    const _Float16* EMBP;    // [10000][128]
    const _Float16* W0XT;    // [1024][128]
    const _Float16* W0HT;    // [1024][1024]
    const _Float16* W1XT;    // [1024][1024]
    const _Float16* W1HT;    // [1024][1024]
    const float* b0; const float* b1;
    _Float16* H00; _Float16* H01;   // h0 ping-pong
    _Float16* H10; _Float16* H11;   // h1 ping-pong
    const float* wout; const float* bout; float* out;
    unsigned* cnt;           // grid-sync counter (zeroed per call)
};

// z = 0 (blocks 0..255):   l1 task — h1_{it-1} = tanh(h0_{it-1}@W1x + h1_{it-2}@W1h + b1), it in [1,80]
// z = 1 (blocks 256..511): l0 task — h0_{it}   = tanh(emb[x[:,it]]@W0x + h0_{it-1}@W0h + b0), it in [0,79]
__launch_bounds__(256, 2)
__global__ void rnn_kernel(PArgs P) {
    __shared__ _Float16 As[2][64 * KC];   // 2 x 16 KB, XOR-8 swizzled
    __shared__ _Float16 Bs[2][64 * KC];   // 2 x 16 KB  (total 64 KB -> 2 blocks/CU)

    const int tid  = threadIdx.x;
    const int lane = tid & 63, w = tid >> 6;
    const int wm = w >> 1, wn = w & 1;
    const int quad = lane >> 4, l16 = lane & 15;

    const int b   = blockIdx.x;          // 0..511
    const int z   = b >> 8;              // task select
    const int bid = b & 255;
    // XCD-aware 4x8 tile clustering (b and bid agree mod 8)
    const int xcd = bid & 7, loc = bid >> 3;
    const int col0 = (((xcd & 3) << 2) | (loc & 3)) << 6;
    const int row0 = (((xcd >> 2) << 3) | (loc >> 2)) << 6;

    // staging geometry: wave-instr g = w*4+q covers rows [g*4, g*4+4), lane l ->
    // row r = g*4 + (l>>4), stored unit u' = l&15, logical unit u = u' ^ (r&7)
    int rr[4], goff[4], arow[4];
    #pragma unroll
    for (int q = 0; q < 4; ++q) {
        int g = w * 4 + q;
        int r = g * 4 + (lane >> 4);
        rr[q]   = g * 512;                        // LDS base (halves)
        goff[q] = 8 * ((lane & 15) ^ (r & 7));    // swizzled k-offset (halves)
        arow[q] = r;
    }

    // iteration-invariant B (weight) panel pointers
    const _Float16* B0T = z ? P.W0XT : P.W1XT;
    const _Float16* B1T = z ? P.W0HT : P.W1HT;
    const int  ldb0  = z ? EPAD : UNITS;
    const int  nch0_ = z ? 1 : 8;
    const int  nch_  = nch0_ + 8;
    const float* bias = z ? P.b0 : P.b1;
    const _Float16* b0p[4]; const _Float16* b1p[4];
    #pragma unroll
    for (int q = 0; q < 4; ++q) {
        b0p[q] = B0T + (size_t)(col0 + arow[q]) * ldb0  + goff[q];
        b1p[q] = B1T + (size_t)(col0 + arow[q]) * UNITS + goff[q];
    }

    _Float16* Hh0[2] = { P.H00, P.H01 };
    _Float16* Hh1[2] = { P.H10, P.H11 };

    unsigned target = 0;
    for (int it = 0; it <= SEQ; ++it) {
        const int p = it & 1;
        const bool active = z ? (it < SEQ) : (it >= 1);
        if (active) {
            const _Float16* a0p[4]; const _Float16* a1p[4];
            _Float16* outp;
            if (z) {                      // l0: out h0_it
                outp = Hh0[p];
                const _Float16* a1b = Hh0[p ^ 1];
                #pragma unroll
                for (int q = 0; q < 4; ++q) {
                    int xi = P.x[(size_t)(row0 + arow[q]) * SEQ + it];
                    a0p[q] = P.EMBP + (size_t)xi * EPAD + goff[q];
                    a1p[q] = a1b + (size_t)(row0 + arow[q]) * UNITS + goff[q];
                }
            } else {                      // l1: out h1_{it-1}
                outp = Hh1[p ^ 1];
                const _Float16* a0b = Hh0[p ^ 1];
                const _Float16* a1b = Hh1[p];
                #pragma unroll
                for (int q = 0; q < 4; ++q) {
                    a0p[q] = a0b + (size_t)(row0 + arow[q]) * UNITS + goff[q];
                    a1p[q] = a1b + (size_t)(row0 + arow[q]) * UNITS + goff[q];
                }
            }

            f4v acc[2][2] = {};

            auto issue = [&](int c, int buf) {
                #pragma unroll
                for (int q = 0; q < 4; ++q) {
                    const _Float16* ap; const _Float16* bp;
                    if (c < nch0_) { ap = a0p[q] + c * KC; bp = b0p[q] + c * KC; }
                    else { int cc = c - nch0_; ap = a1p[q] + cc * KC; bp = b1p[q] + cc * KC; }
                    gl_lds16(ap, &As[buf][0] + rr[q]);
                    gl_lds16(bp, &Bs[buf][0] + rr[q]);
                }
            };

            issue(0, 0);
            for (int c = 0; c < nch_; ++c) {
                const int cur = c & 1;
                if (c + 1 < nch_) {
                    issue(c + 1, cur ^ 1);                        // next chunk in flight
                    asm volatile("s_waitcnt vmcnt(8)" ::: "memory");   // my chunk-c landed
                } else {
                    asm volatile("s_waitcnt vmcnt(0)" ::: "memory");
                }
                __builtin_amdgcn_s_barrier();
                __builtin_amdgcn_sched_barrier(0);
                #pragma unroll
                for (int kk = 0; kk < 4; ++kk) {
                    int us = 8 * ((kk * 4 + quad) ^ (l16 & 7));
                    h8v af[2], bf[2];
                    #pragma unroll
                    for (int i = 0; i < 2; ++i)
                        af[i] = *(const h8v*)(&As[cur][0] + (wm * 32 + i * 16 + l16) * KC + us);
                    #pragma unroll
                    for (int j = 0; j < 2; ++j)
                        bf[j] = *(const h8v*)(&Bs[cur][0] + (wn * 32 + j * 16 + l16) * KC + us);
                    #pragma unroll
                    for (int i = 0; i < 2; ++i)
                        #pragma unroll
                        for (int j = 0; j < 2; ++j)
                            acc[i][j] = __builtin_amdgcn_mfma_f32_16x16x32_f16(
                                af[i], bf[j], acc[i][j], 0, 0, 0);
                }
                __builtin_amdgcn_sched_barrier(0);
                __builtin_amdgcn_s_barrier();
            }

            #pragma unroll
            for (int i = 0; i < 2; ++i) {
                int r = row0 + wm * 32 + i * 16 + quad * 4;
                #pragma unroll
                for (int j = 0; j < 2; ++j) {
                    int cc = col0 + wn * 32 + j * 16 + l16;
                    float bv = bias[cc];
                    #pragma unroll
                    for (int g = 0; g < 4; ++g) {
                        float v = tanh_fast(acc[i][j][g] + bv);
                        outp[(size_t)(r + g) * UNITS + cc] = (_Float16)v;
                    }
                }
            }
        }

        // ---- grid sync: monotonic counter, release-add / acquire-spin ----
        __syncthreads();                 // drains this block's stores (vmcnt) pre-release
        target += GRID;
        if (tid == 0) {
            __hip_atomic_fetch_add(P.cnt, 1u, __ATOMIC_RELEASE, __HIP_MEMORY_SCOPE_AGENT);
            while (__hip_atomic_load(P.cnt, __ATOMIC_ACQUIRE, __HIP_MEMORY_SCOPE_AGENT) < target)
                __builtin_amdgcn_s_sleep(4);
        }
        __syncthreads();                 // block proceeds only after acquire
    }

    // tail: out[b] = sigmoid(h1_79[b] . wout + bout); h1_79 = H11
    if (b < 256) {
        int row = b * 4 + (tid >> 6);
        const _Float16* hr = P.H11 + (size_t)row * UNITS;
        float sacc = 0.f;
        #pragma unroll
        for (int i = 0; i < 16; ++i)
            sacc += (float)hr[i * 64 + lane] * P.wout[i * 64 + lane];
        #pragma unroll
        for (int off = 32; off; off >>= 1) sacc += __shfl_down(sacc, off);
        if ((lane == 0) && ((tid >> 6) == (tid >> 6)))   // lane 0 of each wave
            if (lane == 0) P.out[row] = 1.f / (1.f + __expf(-(sacc + P.bout[0])));
    }
}

extern "C" void kernel_launch(void* const* d_in, const int* in_sizes, int n_in,
                              void* d_out, int out_size, void* d_ws, size_t ws_size,
                              hipStream_t stream) {
    const int*   x    = (const int*)d_in[0];
    const float* emb  = (const float*)d_in[1];
    const float* W0x  = (const float*)d_in[2];
    const float* W0h  = (const float*)d_in[3];
    const float* b0   = (const float*)d_in[4];
    const float* W1x  = (const float*)d_in[5];
    const float* W1h  = (const float*)d_in[6];
    const float* b1   = (const float*)d_in[7];
    const float* Wout = (const float*)d_in[8];
    const float* bout = (const float*)d_in[9];
    float* out = (float*)d_out;

    char* ws = (char*)d_ws;
    _Float16* EMBP = (_Float16*)ws;                          // 10000*128*2 = 2,560,000 B
    _Float16* W0XT = (_Float16*)(ws + 2560000);              // [1024][128]  = 262,144 B
    _Float16* W0HT = W0XT + 1024 * EPAD;                     // [1024][1024] x3
    _Float16* W1XT = W0HT + 1024 * 1024;
    _Float16* W1HT = W1XT + 1024 * 1024;
    _Float16* Hbuf = W1HT + 1024 * 1024;                     // 4 x 2 MB
    _Float16* H00 = Hbuf;
    _Float16* H01 = Hbuf + 1024 * 1024;
    _Float16* H10 = Hbuf + 2 * 1024 * 1024;
    _Float16* H11 = Hbuf + 3 * 1024 * 1024;
    unsigned* CNT = (unsigned*)((char*)(Hbuf + 4 * 1024 * 1024));

    embp_kernel<<<10000, EPAD, 0, stream>>>(emb, EMBP);
    tpad_kernel<<<dim3(4, 32),  dim3(32, 8), 0, stream>>>(W0x, W0XT, EMBD, EPAD, UNITS);
    tpad_kernel<<<dim3(32, 32), dim3(32, 8), 0, stream>>>(W0h, W0HT, UNITS, UNITS, UNITS);
    tpad_kernel<<<dim3(32, 32), dim3(32, 8), 0, stream>>>(W1x, W1XT, UNITS, UNITS, UNITS);
    tpad_kernel<<<dim3(32, 32), dim3(32, 8), 0, stream>>>(W1h, W1HT, UNITS, UNITS, UNITS);
    zero_kernel<<<2049, 256, 0, stream>>>((s8v*)Hbuf, CNT);  // H buffers + sync counter

    PArgs P;
    P.x = x; P.EMBP = EMBP;
    P.W0XT = W0XT; P.W0HT = W0HT; P.W1XT = W1XT; P.W1HT = W1HT;
    P.b0 = b0; P.b1 = b1;
    P.H00 = H00; P.H01 = H01; P.H10 = H10; P.H11 = H11;
    P.wout = Wout; P.bout = bout; P.out = out;
    P.cnt = CNT;
    rnn_kernel<<<GRID, 256, 0, stream>>>(P);
}

// Round 4
// 3005.906 us; speedup vs baseline: 2.1788x; 2.1788x over previous
//
#include <hip/hip_runtime.h>

// MyRnn: 2-layer SimpleRNN, B=1024 T=80 U=1024 E=100. f32 I/O, f16 MFMA compute.
// v6 (resubmit — R3 was a GPU-acquisition infra failure, no data):
// persistent kernel (one dispatch for the 80-step recurrence) with hierarchical
// grid barrier: 8 per-group release-FAA arrival lines -> root, single root
// poller (block 0), per-group epoch broadcast, RELAXED polling + one trailing
// acquire per iteration. GEMM interior = counted-vmcnt double-buffer pipeline
// + s_setprio around the MFMA cluster.

typedef _Float16 h8v __attribute__((ext_vector_type(8)));
typedef float    f4v __attribute__((ext_vector_type(4)));
typedef short    s8v __attribute__((ext_vector_type(8)));

#define UNITS 1024
#define SEQ   80
#define EMBD  100
#define EPAD  128
#define KC    128
#define GRID  512

__device__ __forceinline__ float tanh_fast(float x) {
    x = fminf(15.f, fmaxf(-15.f, x));   // also scrubs NaN
    float e = __expf(2.f * x);
    return (e - 1.f) / (e + 1.f);
}

__device__ __forceinline__ void gl_lds16(const _Float16* g, _Float16* l) {
    __builtin_amdgcn_global_load_lds(
        (const __attribute__((address_space(1))) void*)g,
        (__attribute__((address_space(3))) void*)l, 16, 0, 0);
}

// embp[r][k] = k<100 ? (f16)emb[r][k] : 0   (10000 x 128)
__global__ void embp_kernel(const float* __restrict__ emb, _Float16* __restrict__ embp) {
    int r = blockIdx.x, k = threadIdx.x;
    embp[r * EPAD + k] = (k < EMBD) ? (_Float16)emb[r * EMBD + k] : (_Float16)0.f;
}

// wt[n][kp] = kp<K ? (f16)w[kp][n] : 0 ; wt row stride Kpad. block (32,8).
__global__ void tpad_kernel(const float* __restrict__ w, _Float16* __restrict__ wt,
                            int K, int Kpad, int N) {
    __shared__ float t[32][33];
    int k0 = blockIdx.x * 32, n0 = blockIdx.y * 32;
    int tx = threadIdx.x, ty = threadIdx.y;
    for (int i = ty; i < 32; i += 8) {
        int k = k0 + i;
        t[i][tx] = (k < K) ? w[(size_t)k * N + n0 + tx] : 0.f;
    }
    __syncthreads();
    for (int i = ty; i < 32; i += 8)
        wt[(size_t)(n0 + i) * Kpad + k0 + tx] = (_Float16)t[tx][i];
}

// blocks 0..2047 zero the 8 MB H region; block 2048 zeros the sync block (2 KB)
__global__ void zero_kernel(s8v* __restrict__ p, unsigned* __restrict__ sync) {
    if (blockIdx.x == 2048) {
        if (threadIdx.x < 512) sync[threadIdx.x] = 0u;
        return;
    }
    p[blockIdx.x * 256 + threadIdx.x] = (s8v)0;
}

// sync layout (u32 words): xcnt[g] at [g*16], root at [128], epoch[g] at [144+g*16]
struct PArgs {
    const int* x;            // [1024][80]
    const _Float16* EMBP;    // [10000][128]
    const _Float16* W0XT;    // [1024][128]
    const _Float16* W0HT;    // [1024][1024]
    const _Float16* W1XT;    // [1024][1024]
    const _Float16* W1HT;    // [1024][1024]
    const float* b0; const float* b1;
    _Float16* H00; _Float16* H01;   // h0 ping-pong
    _Float16* H10; _Float16* H11;   // h1 ping-pong
    const float* wout; const float* bout; float* out;
    unsigned* sync;
};

// z = 0 (blocks 0..255):   l1 task — h1_{it-1} = tanh(h0_{it-1}@W1x + h1_{it-2}@W1h + b1), it in [1,80]
// z = 1 (blocks 256..511): l0 task — h0_{it}   = tanh(emb[x[:,it]]@W0x + h0_{it-1}@W0h + b0), it in [0,79]
__launch_bounds__(256, 2)
__global__ void rnn_kernel(PArgs P) {
    __shared__ _Float16 As[2][64 * KC];   // 2 x 16 KB, XOR-8 swizzled
    __shared__ _Float16 Bs[2][64 * KC];   // 2 x 16 KB  (total 64 KB -> 2 blocks/CU)

    const int tid  = threadIdx.x;
    const int lane = tid & 63, w = tid >> 6;
    const int wm = w >> 1, wn = w & 1;
    const int quad = lane >> 4, l16 = lane & 15;

    const int b   = blockIdx.x;          // 0..511
    const int z   = b >> 8;              // task select
    const int bid = b & 255;
    // XCD-aware 4x8 tile clustering (perf heuristic only; correctness-free)
    const int xcd = bid & 7, loc = bid >> 3;
    const int col0 = (((xcd & 3) << 2) | (loc & 3)) << 6;
    const int row0 = (((xcd >> 2) << 3) | (loc >> 2)) << 6;

    // staging geometry: wave-instr g = w*4+q covers rows [g*4, g*4+4), lane l ->
    // row r = g*4 + (l>>4), stored unit u' = l&15, logical unit u = u' ^ (r&7)
    int rr[4], goff[4], arow[4];
    #pragma unroll
    for (int q = 0; q < 4; ++q) {
        int g = w * 4 + q;
        int r = g * 4 + (lane >> 4);
        rr[q]   = g * 512;                        // LDS base (halves)
        goff[q] = 8 * ((lane & 15) ^ (r & 7));    // swizzled k-offset (halves)
        arow[q] = r;
    }

    // iteration-invariant B (weight) panel pointers
    const _Float16* B0T = z ? P.W0XT : P.W1XT;
    const _Float16* B1T = z ? P.W0HT : P.W1HT;
    const int  ldb0  = z ? EPAD : UNITS;
    const int  nch0_ = z ? 1 : 8;
    const int  nch_  = nch0_ + 8;
    const float* bias = z ? P.b0 : P.b1;
    const _Float16* b0p[4]; const _Float16* b1p[4];
    #pragma unroll
    for (int q = 0; q < 4; ++q) {
        b0p[q] = B0T + (size_t)(col0 + arow[q]) * ldb0  + goff[q];
        b1p[q] = B1T + (size_t)(col0 + arow[q]) * UNITS + goff[q];
    }

    _Float16* Hh0[2] = { P.H00, P.H01 };
    _Float16* Hh1[2] = { P.H10, P.H11 };

    unsigned* xcnt  = P.sync + (b & 7) * 16;
    unsigned* root  = P.sync + 128;
    unsigned* epoch = P.sync + 144 + (b & 7) * 16;

    for (int it = 0; it <= SEQ; ++it) {
        const int p = it & 1;
        const bool active = z ? (it < SEQ) : (it >= 1);
        if (active) {
            const _Float16* a0p[4]; const _Float16* a1p[4];
            _Float16* outp;
            if (z) {                      // l0: out h0_it
                outp = Hh0[p];
                const _Float16* a1b = Hh0[p ^ 1];
                #pragma unroll
                for (int q = 0; q < 4; ++q) {
                    int xi = P.x[(size_t)(row0 + arow[q]) * SEQ + it];
                    a0p[q] = P.EMBP + (size_t)xi * EPAD + goff[q];
                    a1p[q] = a1b + (size_t)(row0 + arow[q]) * UNITS + goff[q];
                }
            } else {                      // l1: out h1_{it-1}
                outp = Hh1[p ^ 1];
                const _Float16* a0b = Hh0[p ^ 1];
                const _Float16* a1b = Hh1[p];
                #pragma unroll
                for (int q = 0; q < 4; ++q) {
                    a0p[q] = a0b + (size_t)(row0 + arow[q]) * UNITS + goff[q];
                    a1p[q] = a1b + (size_t)(row0 + arow[q]) * UNITS + goff[q];
                }
            }

            f4v acc[2][2] = {};

            auto issue = [&](int c, int buf) {
                #pragma unroll
                for (int q = 0; q < 4; ++q) {
                    const _Float16* ap; const _Float16* bp;
                    if (c < nch0_) { ap = a0p[q] + c * KC; bp = b0p[q] + c * KC; }
                    else { int cc = c - nch0_; ap = a1p[q] + cc * KC; bp = b1p[q] + cc * KC; }
                    gl_lds16(ap, &As[buf][0] + rr[q]);
                    gl_lds16(bp, &Bs[buf][0] + rr[q]);
                }
            };

            issue(0, 0);
            for (int c = 0; c < nch_; ++c) {
                const int cur = c & 1;
                if (c + 1 < nch_) {
                    issue(c + 1, cur ^ 1);                        // next chunk in flight
                    asm volatile("s_waitcnt vmcnt(8)" ::: "memory");   // my chunk-c landed
                } else {
                    asm volatile("s_waitcnt vmcnt(0)" ::: "memory");
                }
                __builtin_amdgcn_s_barrier();
                __builtin_amdgcn_sched_barrier(0);
                __builtin_amdgcn_s_setprio(1);
                #pragma unroll
                for (int kk = 0; kk < 4; ++kk) {
                    int us = 8 * ((kk * 4 + quad) ^ (l16 & 7));
                    h8v af[2], bf[2];
                    #pragma unroll
                    for (int i = 0; i < 2; ++i)
                        af[i] = *(const h8v*)(&As[cur][0] + (wm * 32 + i * 16 + l16) * KC + us);
                    #pragma unroll
                    for (int j = 0; j < 2; ++j)
                        bf[j] = *(const h8v*)(&Bs[cur][0] + (wn * 32 + j * 16 + l16) * KC + us);
                    #pragma unroll
                    for (int i = 0; i < 2; ++i)
                        #pragma unroll
                        for (int j = 0; j < 2; ++j)
                            acc[i][j] = __builtin_amdgcn_mfma_f32_16x16x32_f16(
                                af[i], bf[j], acc[i][j], 0, 0, 0);
                }
                __builtin_amdgcn_s_setprio(0);
                __builtin_amdgcn_sched_barrier(0);
                __builtin_amdgcn_s_barrier();
            }

            #pragma unroll
            for (int i = 0; i < 2; ++i) {
                int r = row0 + wm * 32 + i * 16 + quad * 4;
                #pragma unroll
                for (int j = 0; j < 2; ++j) {
                    int cc = col0 + wn * 32 + j * 16 + l16;
                    float bv = bias[cc];
                    #pragma unroll
                    for (int g = 0; g < 4; ++g) {
                        float v = tanh_fast(acc[i][j][g] + bv);
                        outp[(size_t)(r + g) * UNITS + cc] = (_Float16)v;
                    }
                }
            }
        }

        // ---- hierarchical grid barrier (monotonic epochs, relaxed polling) ----
        const unsigned tgt = (unsigned)(it + 1);
        __syncthreads();                 // drains this block's stores (vmcnt0) pre-release
        if (tid == 0) {
            // arrival: release-FAA publishes this block's h-writes (per-block release
            // so every XCD's L2 gets written back regardless of block->XCD mapping)
            unsigned r = __hip_atomic_fetch_add(xcnt, 1u, __ATOMIC_RELEASE,
                                                __HIP_MEMORY_SCOPE_AGENT);
            if ((r & 63u) == 63u)        // group complete -> promote to root
                __hip_atomic_fetch_add(root, 1u, __ATOMIC_RELEASE,
                                       __HIP_MEMORY_SCOPE_AGENT);
            if (b == 0) {
                // single root poller, then per-group epoch broadcast
                while (__hip_atomic_load(root, __ATOMIC_RELAXED,
                                         __HIP_MEMORY_SCOPE_AGENT) < 8u * tgt)
                    __builtin_amdgcn_s_sleep(8);
                #pragma unroll
                for (int xx = 0; xx < 8; ++xx)
                    __hip_atomic_store(P.sync + 144 + xx * 16, tgt, __ATOMIC_RELAXED,
                                       __HIP_MEMORY_SCOPE_AGENT);
            }
            // relaxed spin on this group's epoch (no buffer_inv per poll)
            while (__hip_atomic_load(epoch, __ATOMIC_RELAXED,
                                     __HIP_MEMORY_SCOPE_AGENT) < tgt)
                __builtin_amdgcn_s_sleep(8);
            // one acquire to pull coherence (buffer_inv) exactly once per iteration
            (void)__hip_atomic_load(epoch, __ATOMIC_ACQUIRE, __HIP_MEMORY_SCOPE_AGENT);
        }
        __syncthreads();                 // block proceeds only after acquire
    }

    // tail: out[b] = sigmoid(h1_79[b] . wout + bout); h1_79 = H11
    if (b < 256) {
        int row = b * 4 + (tid >> 6);
        const _Float16* hr = P.H11 + (size_t)row * UNITS;
        float sacc = 0.f;
        #pragma unroll
        for (int i = 0; i < 16; ++i)
            sacc += (float)hr[i * 64 + lane] * P.wout[i * 64 + lane];
        #pragma unroll
        for (int off = 32; off; off >>= 1) sacc += __shfl_down(sacc, off);
        if (lane == 0)
            P.out[row] = 1.f / (1.f + __expf(-(sacc + P.bout[0])));
    }
}

extern "C" void kernel_launch(void* const* d_in, const int* in_sizes, int n_in,
                              void* d_out, int out_size, void* d_ws, size_t ws_size,
                              hipStream_t stream) {
    const int*   x    = (const int*)d_in[0];
    const float* emb  = (const float*)d_in[1];
    const float* W0x  = (const float*)d_in[2];
    const float* W0h  = (const float*)d_in[3];
    const float* b0   = (const float*)d_in[4];
    const float* W1x  = (const float*)d_in[5];
    const float* W1h  = (const float*)d_in[6];
    const float* b1   = (const float*)d_in[7];
    const float* Wout = (const float*)d_in[8];
    const float* bout = (const float*)d_in[9];
    float* out = (float*)d_out;

    char* ws = (char*)d_ws;
    _Float16* EMBP = (_Float16*)ws;                          // 10000*128*2 = 2,560,000 B
    _Float16* W0XT = (_Float16*)(ws + 2560000);              // [1024][128]  = 262,144 B
    _Float16* W0HT = W0XT + 1024 * EPAD;                     // [1024][1024] x3
    _Float16* W1XT = W0HT + 1024 * 1024;
    _Float16* W1HT = W1XT + 1024 * 1024;
    _Float16* Hbuf = W1HT + 1024 * 1024;                     // 4 x 2 MB
    _Float16* H00 = Hbuf;
    _Float16* H01 = Hbuf + 1024 * 1024;
    _Float16* H10 = Hbuf + 2 * 1024 * 1024;
    _Float16* H11 = Hbuf + 3 * 1024 * 1024;
    unsigned* SYNC = (unsigned*)((char*)(Hbuf + 4 * 1024 * 1024));

    embp_kernel<<<10000, EPAD, 0, stream>>>(emb, EMBP);
    tpad_kernel<<<dim3(4, 32),  dim3(32, 8), 0, stream>>>(W0x, W0XT, EMBD, EPAD, UNITS);
    tpad_kernel<<<dim3(32, 32), dim3(32, 8), 0, stream>>>(W0h, W0HT, UNITS, UNITS, UNITS);
    tpad_kernel<<<dim3(32, 32), dim3(32, 8), 0, stream>>>(W1x, W1XT, UNITS, UNITS, UNITS);
    tpad_kernel<<<dim3(32, 32), dim3(32, 8), 0, stream>>>(W1h, W1HT, UNITS, UNITS, UNITS);
    zero_kernel<<<2049, 256, 0, stream>>>((s8v*)Hbuf, SYNC); // H buffers + sync block

    PArgs P;
    P.x = x; P.EMBP = EMBP;
    P.W0XT = W0XT; P.W0HT = W0HT; P.W1XT = W1XT; P.W1HT = W1HT;
    P.b0 = b0; P.b1 = b1;
    P.H00 = H00; P.H01 = H01; P.H10 = H10; P.H11 = H11;
    P.wout = Wout; P.bout = bout; P.out = out;
    P.sync = SYNC;
    rnn_kernel<<<GRID, 256, 0, stream>>>(P);
}

// Round 7
// 1652.757 us; speedup vs baseline: 3.9626x; 1.8187x over previous
//
#include <hip/hip_runtime.h>

// MyRnn: 2-layer SimpleRNN, B=1024 T=80 U=1024 E=100. f32 I/O, f16 MFMA compute.
// v7 (resubmit x2 — R5/R6 were GPU-acquisition infra failures, no data):
// persistent kernel with ZERO cache-maintenance steady state.
//   - h-state stores: write-through device-coherent (global_store_short sc0 sc1)
//   - h-state staging loads: global_load_lds aux=0x11 (sc0|sc1, bypass L1/L2)
//   - barrier atomics: RELAXED (no buffer_inv / buffer_wbl2 anywhere in the loop;
//     __syncthreads' vmcnt(0) drain orders WT stores before the arrival FAA)
//   - weights/EMBP/x/bias: cacheable -> L1/L2-resident across all 81 iterations.
// v6's 512 acquire-invs + 512 release-wbl2 walks per iteration re-fetched the
// full 11.25 MB working set from memory every step (FETCH_SIZE 911 MB, 414 GB/s
// latency-bound) — that was ~27 of the 37.5 us/iter.

typedef _Float16 h8v __attribute__((ext_vector_type(8)));
typedef float    f4v __attribute__((ext_vector_type(4)));
typedef short    s8v __attribute__((ext_vector_type(8)));
typedef unsigned int u4v __attribute__((ext_vector_type(4)));

#define UNITS 1024
#define SEQ   80
#define EMBD  100
#define EPAD  128
#define KC    128
#define GRID  512

__device__ __forceinline__ float tanh_fast(float x) {
    x = fminf(15.f, fmaxf(-15.f, x));   // also scrubs NaN
    float e = __expf(2.f * x);
    return (e - 1.f) / (e + 1.f);
}

// cacheable global->LDS (weights, EMBP): L1/L2-resident across iterations
__device__ __forceinline__ void gl_lds16_c(const _Float16* g, _Float16* l) {
    __builtin_amdgcn_global_load_lds(
        (const __attribute__((address_space(1))) void*)g,
        (__attribute__((address_space(3))) void*)l, 16, 0, 0);
}
// device-coherent bypass global->LDS (h-state): aux = sc0|sc1 = 0x11
__device__ __forceinline__ void gl_lds16_v(const _Float16* g, _Float16* l) {
    __builtin_amdgcn_global_load_lds(
        (const __attribute__((address_space(1))) void*)g,
        (__attribute__((address_space(3))) void*)l, 16, 0, 0x11);
}
// write-through device-coherent 2B store (h-state)
__device__ __forceinline__ void st2_wt(_Float16* p, float v) {
    _Float16 h = (_Float16)v;
    unsigned int uv = (unsigned int)__builtin_bit_cast(unsigned short, h);
    asm volatile("global_store_short %0, %1, off sc0 sc1" :: "v"(p), "v"(uv) : "memory");
}
// device-coherent 16B load (tail h read)
__device__ __forceinline__ u4v ld16_v(const void* p) {
    u4v r;
    asm volatile("global_load_dwordx4 %0, %1, off sc0 sc1\n\ts_waitcnt vmcnt(0)"
                 : "=v"(r) : "v"(p) : "memory");
    return r;
}
// write-through 16B store (h zero-init must land at IF for bypass readers)
__device__ __forceinline__ void st16_wt(void* p, u4v v) {
    asm volatile("global_store_dwordx4 %0, %1, off sc0 sc1" :: "v"(p), "v"(v) : "memory");
}

// embp[r][k] = k<100 ? (f16)emb[r][k] : 0   (10000 x 128)
__global__ void embp_kernel(const float* __restrict__ emb, _Float16* __restrict__ embp) {
    int r = blockIdx.x, k = threadIdx.x;
    embp[r * EPAD + k] = (k < EMBD) ? (_Float16)emb[r * EMBD + k] : (_Float16)0.f;
}

// wt[n][kp] = kp<K ? (f16)w[kp][n] : 0 ; wt row stride Kpad. block (32,8).
__global__ void tpad_kernel(const float* __restrict__ w, _Float16* __restrict__ wt,
                            int K, int Kpad, int N) {
    __shared__ float t[32][33];
    int k0 = blockIdx.x * 32, n0 = blockIdx.y * 32;
    int tx = threadIdx.x, ty = threadIdx.y;
    for (int i = ty; i < 32; i += 8) {
        int k = k0 + i;
        t[i][tx] = (k < K) ? w[(size_t)k * N + n0 + tx] : 0.f;
    }
    __syncthreads();
    for (int i = ty; i < 32; i += 8)
        wt[(size_t)(n0 + i) * Kpad + k0 + tx] = (_Float16)t[tx][i];
}

// blocks 0..2047: zero 8 MB H region WRITE-THROUGH; block 2048: zero sync words
__global__ void zero_kernel(char* __restrict__ p, unsigned* __restrict__ sync) {
    if (blockIdx.x == 2048) {
        if (threadIdx.x < 512)
            __hip_atomic_store(sync + threadIdx.x, 0u, __ATOMIC_RELAXED,
                               __HIP_MEMORY_SCOPE_AGENT);
        return;
    }
    u4v z = {0u, 0u, 0u, 0u};
    st16_wt(p + ((size_t)blockIdx.x * 256 + threadIdx.x) * 16, z);
}

// sync layout (u32 words): xcnt[g] at [g*16], root at [128], epoch[g] at [144+g*16]
struct PArgs {
    const int* x;            // [1024][80]
    const _Float16* EMBP;    // [10000][128]
    const _Float16* W0XT;    // [1024][128]
    const _Float16* W0HT;    // [1024][1024]
    const _Float16* W1XT;    // [1024][1024]
    const _Float16* W1HT;    // [1024][1024]
    const float* b0; const float* b1;
    _Float16* H00; _Float16* H01;   // h0 ping-pong
    _Float16* H10; _Float16* H11;   // h1 ping-pong
    const float* wout; const float* bout; float* out;
    unsigned* sync;
};

// z = 0 (blocks 0..255):   l1 task — h1_{it-1} = tanh(h0_{it-1}@W1x + h1_{it-2}@W1h + b1), it in [1,80]
// z = 1 (blocks 256..511): l0 task — h0_{it}   = tanh(emb[x[:,it]]@W0x + h0_{it-1}@W0h + b0), it in [0,79]
__launch_bounds__(256, 2)
__global__ void rnn_kernel(PArgs P) {
    __shared__ _Float16 As[2][64 * KC];   // 2 x 16 KB, XOR-8 swizzled
    __shared__ _Float16 Bs[2][64 * KC];   // 2 x 16 KB  (total 64 KB -> 2 blocks/CU)

    const int tid  = threadIdx.x;
    const int lane = tid & 63, w = tid >> 6;
    const int wm = w >> 1, wn = w & 1;
    const int quad = lane >> 4, l16 = lane & 15;

    const int b   = blockIdx.x;          // 0..511
    const int z   = b >> 8;              // task select
    const int bid = b & 255;
    // XCD-aware 4x8 tile clustering (perf heuristic only; correctness-free)
    const int xcd = bid & 7, loc = bid >> 3;
    const int col0 = (((xcd & 3) << 2) | (loc & 3)) << 6;
    const int row0 = (((xcd >> 2) << 3) | (loc >> 2)) << 6;

    // staging geometry: wave-instr g = w*4+q covers rows [g*4, g*4+4), lane l ->
    // row r = g*4 + (l>>4), stored unit u' = l&15, logical unit u = u' ^ (r&7)
    int rr[4], goff[4], arow[4];
    #pragma unroll
    for (int q = 0; q < 4; ++q) {
        int g = w * 4 + q;
        int r = g * 4 + (lane >> 4);
        rr[q]   = g * 512;                        // LDS base (halves)
        goff[q] = 8 * ((lane & 15) ^ (r & 7));    // swizzled k-offset (halves)
        arow[q] = r;
    }

    // iteration-invariant B (weight) panel pointers — cacheable, L2-hot
    const _Float16* B0T = z ? P.W0XT : P.W1XT;
    const _Float16* B1T = z ? P.W0HT : P.W1HT;
    const int  ldb0  = z ? EPAD : UNITS;
    const int  nch0_ = z ? 1 : 8;
    const int  nch_  = nch0_ + 8;
    const float* bias = z ? P.b0 : P.b1;
    const _Float16* b0p[4]; const _Float16* b1p[4];
    #pragma unroll
    for (int q = 0; q < 4; ++q) {
        b0p[q] = B0T + (size_t)(col0 + arow[q]) * ldb0  + goff[q];
        b1p[q] = B1T + (size_t)(col0 + arow[q]) * UNITS + goff[q];
    }

    _Float16* Hh0[2] = { P.H00, P.H01 };
    _Float16* Hh1[2] = { P.H10, P.H11 };

    unsigned* xcnt  = P.sync + (b & 7) * 16;
    unsigned* root  = P.sync + 128;
    unsigned* epoch = P.sync + 144 + (b & 7) * 16;

    for (int it = 0; it <= SEQ; ++it) {
        const int p = it & 1;
        const bool active = z ? (it < SEQ) : (it >= 1);
        if (active) {
            const _Float16* a0p[4]; const _Float16* a1p[4];
            _Float16* outp;
            if (z) {                      // l0: out h0_it
                outp = Hh0[p];
                const _Float16* a1b = Hh0[p ^ 1];
                #pragma unroll
                for (int q = 0; q < 4; ++q) {
                    int xi = P.x[(size_t)(row0 + arow[q]) * SEQ + it];
                    a0p[q] = P.EMBP + (size_t)xi * EPAD + goff[q];
                    a1p[q] = a1b + (size_t)(row0 + arow[q]) * UNITS + goff[q];
                }
            } else {                      // l1: out h1_{it-1}
                outp = Hh1[p ^ 1];
                const _Float16* a0b = Hh0[p ^ 1];
                const _Float16* a1b = Hh1[p];
                #pragma unroll
                for (int q = 0; q < 4; ++q) {
                    a0p[q] = a0b + (size_t)(row0 + arow[q]) * UNITS + goff[q];
                    a1p[q] = a1b + (size_t)(row0 + arow[q]) * UNITS + goff[q];
                }
            }

            f4v acc[2][2] = {};

            // A-side: h-state panels bypass (always for l1; source-1 for l0);
            // EMBP (l0 source-0) cacheable. B-side (weights) always cacheable.
            auto issue = [&](int c, int buf) {
                #pragma unroll
                for (int q = 0; q < 4; ++q) {
                    const _Float16* ap; const _Float16* bp; bool byp;
                    if (c < nch0_) { ap = a0p[q] + c * KC; bp = b0p[q] + c * KC; byp = (z == 0); }
                    else { int cc = c - nch0_; ap = a1p[q] + cc * KC; bp = b1p[q] + cc * KC; byp = true; }
                    if (byp) gl_lds16_v(ap, &As[buf][0] + rr[q]);
                    else     gl_lds16_c(ap, &As[buf][0] + rr[q]);
                    gl_lds16_c(bp, &Bs[buf][0] + rr[q]);
                }
            };

            issue(0, 0);
            for (int c = 0; c < nch_; ++c) {
                const int cur = c & 1;
                if (c + 1 < nch_) {
                    issue(c + 1, cur ^ 1);                        // next chunk in flight
                    asm volatile("s_waitcnt vmcnt(8)" ::: "memory");   // my chunk-c landed
                } else {
                    asm volatile("s_waitcnt vmcnt(0)" ::: "memory");
                }
                __builtin_amdgcn_s_barrier();
                __builtin_amdgcn_sched_barrier(0);
                #pragma unroll
                for (int kk = 0; kk < 4; ++kk) {
                    int us = 8 * ((kk * 4 + quad) ^ (l16 & 7));
                    h8v af[2], bf[2];
                    #pragma unroll
                    for (int i = 0; i < 2; ++i)
                        af[i] = *(const h8v*)(&As[cur][0] + (wm * 32 + i * 16 + l16) * KC + us);
                    #pragma unroll
                    for (int j = 0; j < 2; ++j)
                        bf[j] = *(const h8v*)(&Bs[cur][0] + (wn * 32 + j * 16 + l16) * KC + us);
                    #pragma unroll
                    for (int i = 0; i < 2; ++i)
                        #pragma unroll
                        for (int j = 0; j < 2; ++j)
                            acc[i][j] = __builtin_amdgcn_mfma_f32_16x16x32_f16(
                                af[i], bf[j], acc[i][j], 0, 0, 0);
                }
                __builtin_amdgcn_sched_barrier(0);
                __builtin_amdgcn_s_barrier();
            }

            // epilogue: write-through device-coherent h stores (no dirty L2 lines)
            #pragma unroll
            for (int i = 0; i < 2; ++i) {
                int r = row0 + wm * 32 + i * 16 + quad * 4;
                #pragma unroll
                for (int j = 0; j < 2; ++j) {
                    int cc = col0 + wn * 32 + j * 16 + l16;
                    float bv = bias[cc];
                    #pragma unroll
                    for (int g = 0; g < 4; ++g)
                        st2_wt(outp + (size_t)(r + g) * UNITS + cc,
                               tanh_fast(acc[i][j][g] + bv));
                }
            }
        }

        // ---- grid barrier: relaxed atomics only (no inv, no wbl2) ----
        // __syncthreads drains vmcnt(0): all WT h-stores are at the coherent
        // point before the arrival FAA becomes visible.
        const unsigned tgt = (unsigned)(it + 1);
        __syncthreads();
        if (tid == 0) {
            unsigned r = __hip_atomic_fetch_add(xcnt, 1u, __ATOMIC_RELAXED,
                                                __HIP_MEMORY_SCOPE_AGENT);
            if ((r & 63u) == 63u)        // group complete -> promote to root
                __hip_atomic_fetch_add(root, 1u, __ATOMIC_RELAXED,
                                       __HIP_MEMORY_SCOPE_AGENT);
            if (b == 0) {
                while (__hip_atomic_load(root, __ATOMIC_RELAXED,
                                         __HIP_MEMORY_SCOPE_AGENT) < 8u * tgt)
                    __builtin_amdgcn_s_sleep(8);
                #pragma unroll
                for (int xx = 0; xx < 8; ++xx)
                    __hip_atomic_store(P.sync + 144 + xx * 16, tgt, __ATOMIC_RELAXED,
                                       __HIP_MEMORY_SCOPE_AGENT);
            }
            while (__hip_atomic_load(epoch, __ATOMIC_RELAXED,
                                     __HIP_MEMORY_SCOPE_AGENT) < tgt)
                __builtin_amdgcn_s_sleep(2);
        }
        __syncthreads();
    }

    // tail: out[b] = sigmoid(h1_79[b] . wout + bout); h1_79 = H11 (bypass reads)
    if (b < 256) {
        int row = b * 4 + (tid >> 6);
        const _Float16* hr = P.H11 + (size_t)row * UNITS;
        u4v d0 = ld16_v(hr + lane * 16);
        u4v d1 = ld16_v(hr + lane * 16 + 8);
        float sacc = 0.f;
        #pragma unroll
        for (int i = 0; i < 4; ++i) {
            unsigned w0 = d0[i], w1 = d1[i];
            _Float16 h0 = __builtin_bit_cast(_Float16, (unsigned short)(w0 & 0xffffu));
            _Float16 h1 = __builtin_bit_cast(_Float16, (unsigned short)(w0 >> 16));
            _Float16 h2 = __builtin_bit_cast(_Float16, (unsigned short)(w1 & 0xffffu));
            _Float16 h3 = __builtin_bit_cast(_Float16, (unsigned short)(w1 >> 16));
            sacc += (float)h0 * P.wout[lane * 16 + 2 * i + 0];
            sacc += (float)h1 * P.wout[lane * 16 + 2 * i + 1];
            sacc += (float)h2 * P.wout[lane * 16 + 8 + 2 * i + 0];
            sacc += (float)h3 * P.wout[lane * 16 + 8 + 2 * i + 1];
        }
        #pragma unroll
        for (int off = 32; off; off >>= 1) sacc += __shfl_down(sacc, off);
        if (lane == 0)
            P.out[row] = 1.f / (1.f + __expf(-(sacc + P.bout[0])));
    }
}

extern "C" void kernel_launch(void* const* d_in, const int* in_sizes, int n_in,
                              void* d_out, int out_size, void* d_ws, size_t ws_size,
                              hipStream_t stream) {
    const int*   x    = (const int*)d_in[0];
    const float* emb  = (const float*)d_in[1];
    const float* W0x  = (const float*)d_in[2];
    const float* W0h  = (const float*)d_in[3];
    const float* b0   = (const float*)d_in[4];
    const float* W1x  = (const float*)d_in[5];
    const float* W1h  = (const float*)d_in[6];
    const float* b1   = (const float*)d_in[7];
    const float* Wout = (const float*)d_in[8];
    const float* bout = (const float*)d_in[9];
    float* out = (float*)d_out;

    char* ws = (char*)d_ws;
    _Float16* EMBP = (_Float16*)ws;                          // 10000*128*2 = 2,560,000 B
    _Float16* W0XT = (_Float16*)(ws + 2560000);              // [1024][128]  = 262,144 B
    _Float16* W0HT = W0XT + 1024 * EPAD;                     // [1024][1024] x3
    _Float16* W1XT = W0HT + 1024 * 1024;
    _Float16* W1HT = W1XT + 1024 * 1024;
    _Float16* Hbuf = W1HT + 1024 * 1024;                     // 4 x 2 MB
    _Float16* H00 = Hbuf;
    _Float16* H01 = Hbuf + 1024 * 1024;
    _Float16* H10 = Hbuf + 2 * 1024 * 1024;
    _Float16* H11 = Hbuf + 3 * 1024 * 1024;
    unsigned* SYNC = (unsigned*)((char*)(Hbuf + 4 * 1024 * 1024));

    embp_kernel<<<10000, EPAD, 0, stream>>>(emb, EMBP);
    tpad_kernel<<<dim3(4, 32),  dim3(32, 8), 0, stream>>>(W0x, W0XT, EMBD, EPAD, UNITS);
    tpad_kernel<<<dim3(32, 32), dim3(32, 8), 0, stream>>>(W0h, W0HT, UNITS, UNITS, UNITS);
    tpad_kernel<<<dim3(32, 32), dim3(32, 8), 0, stream>>>(W1x, W1XT, UNITS, UNITS, UNITS);
    tpad_kernel<<<dim3(32, 32), dim3(32, 8), 0, stream>>>(W1h, W1HT, UNITS, UNITS, UNITS);
    zero_kernel<<<2049, 256, 0, stream>>>((char*)Hbuf, SYNC); // WT zeros + sync words

    PArgs P;
    P.x = x; P.EMBP = EMBP;
    P.W0XT = W0XT; P.W0HT = W0HT; P.W1XT = W1XT; P.W1HT = W1HT;
    P.b0 = b0; P.b1 = b1;
    P.H00 = H00; P.H01 = H01; P.H10 = H10; P.H11 = H11;
    P.wout = Wout; P.bout = bout; P.out = out;
    P.sync = SYNC;
    rnn_kernel<<<GRID, 256, 0, stream>>>(P);
}